// Round 1
// baseline (2862.602 us; speedup 1.0000x reference)
//
#include <hip/hip_runtime.h>
#include <cstdint>
#include <cstddef>

#define D 128
#define NPB 32      // nodes per block in GRU kernel
#define XS 132      // padded LDS row stride (floats), 16B-aligned, breaks bank conflicts

__global__ void count_kernel(const int* __restrict__ src, const int* __restrict__ dst,
                             int E, int* __restrict__ cnt) {
    int m = blockIdx.x * blockDim.x + threadIdx.x;
    if (m < E) {
        atomicAdd(&cnt[src[m]], 1);
        atomicAdd(&cnt[dst[m]], 1);
    }
}

// Exclusive offsets via per-wave scan + one ticket atomic per wave.
// Base order across waves is nondeterministic but buckets stay disjoint;
// only float-sum order changes (way below tolerance).
__global__ void offsets_kernel(const int* __restrict__ cnt, int N,
                               int* __restrict__ offs, int* __restrict__ cursor,
                               int* __restrict__ ticket) {
    int i = blockIdx.x * blockDim.x + threadIdx.x;
    int lane = threadIdx.x & 63;
    int c = (i < N) ? cnt[i] : 0;
    // inclusive wave scan
    int pre = c;
    #pragma unroll
    for (int o = 1; o < 64; o <<= 1) {
        int v = __shfl_up(pre, o);
        if (lane >= o) pre += v;
    }
    int total = __shfl(pre, 63);
    int excl  = pre - c;
    int base = 0;
    if (lane == 0) base = atomicAdd(ticket, total);
    base = __shfl(base, 0);
    if (i < N) {
        offs[i]   = base + excl;
        cursor[i] = base + excl;
    }
}

__global__ void fill_kernel(const int* __restrict__ src, const int* __restrict__ dst,
                            int E, int* __restrict__ cursor, int* __restrict__ nb) {
    int m = blockIdx.x * blockDim.x + threadIdx.x;
    if (m < E) {
        int s = src[m], d = dst[m];
        int p1 = atomicAdd(&cursor[s], 1); nb[p1] = d;   // node s receives neighbor d
        int p2 = atomicAdd(&cursor[d], 1); nb[p2] = s;   // node d receives neighbor s
    }
}

__device__ __forceinline__ float dot4(float4 a, float4 b, float acc) {
    acc = fmaf(a.x, b.x, acc);
    acc = fmaf(a.y, b.y, acc);
    acc = fmaf(a.z, b.z, acc);
    acc = fmaf(a.w, b.w, acc);
    return acc;
}

__device__ __forceinline__ float sigmoidf_(float a) {
    return 1.0f / (1.0f + __expf(-a));
}
__device__ __forceinline__ float tanhf_(float a) {
    float e2 = __expf(2.0f * a);
    return 1.0f - 2.0f / (e2 + 1.0f);
}

__global__ __launch_bounds__(256) void gru_kernel(
    const float* __restrict__ feat, const float* __restrict__ mem,
    const float* __restrict__ w_ih, const float* __restrict__ w_hh,
    const float* __restrict__ b_ih, const float* __restrict__ b_hh,
    const int* __restrict__ cnt, const int* __restrict__ offs,
    const int* __restrict__ nb, float* __restrict__ out, int N)
{
    __shared__ float s_x[NPB * XS];
    __shared__ float s_h[NPB * XS];
    __shared__ float s_o[NPB * XS];
    __shared__ int   s_deg[NPB];

    const int tid  = threadIdx.x;
    const int base = blockIdx.x * NPB;

    // ---- phase 1a: stage memory rows (h) into LDS
    for (int idx = tid; idx < NPB * D; idx += 256) {
        int nl = idx >> 7, kk = idx & 127;
        int node = base + nl;
        s_h[nl * XS + kk] = (node < N) ? mem[(size_t)node * D + kk] : 0.0f;
    }

    // ---- phase 1b: gather-mean neighbor features into LDS (x)
    const int wave = tid >> 6, lane = tid & 63;
    for (int q = 0; q < NPB / 4; ++q) {        // each of 4 waves handles NPB/4 nodes
        int nl = wave * (NPB / 4) + q;
        int node = base + nl;
        int deg = (node < N) ? cnt[node] : 0;
        int off = (node < N) ? offs[node] : 0;
        float2 acc = {0.0f, 0.0f};
        for (int e = 0; e < deg; ++e) {
            int nbv = nb[off + e];
            float2 f = *reinterpret_cast<const float2*>(&feat[(size_t)nbv * D + lane * 2]);
            acc.x += f.x; acc.y += f.y;
        }
        float inv = 1.0f / (float)(deg > 0 ? deg : 1);
        s_x[nl * XS + lane * 2]     = acc.x * inv;
        s_x[nl * XS + lane * 2 + 1] = acc.y * inv;
        if (lane == 0) s_deg[nl] = deg;
    }
    __syncthreads();

    // ---- phase 2: GRU. Each thread handles (node n, 4 output dims k0..k0+3).
    // pairs = NPB nodes x 32 kgroups = 1024; 256 threads -> 4 iterations.
    for (int it = 0; it < (NPB * 32) / 256; ++it) {
        int p  = it * 256 + tid;
        int n  = p & (NPB - 1);
        int kg = p >> 5;            // 0..31 (NPB==32)
        int k0 = kg * 4;

        float acc[4][6];
        #pragma unroll
        for (int j = 0; j < 4; ++j)
            #pragma unroll
            for (int q2 = 0; q2 < 6; ++q2) acc[j][q2] = 0.0f;

        const float4* xrow = reinterpret_cast<const float4*>(&s_x[n * XS]);
        const float4* hrow = reinterpret_cast<const float4*>(&s_h[n * XS]);

        #pragma unroll 2
        for (int kk4 = 0; kk4 < 32; ++kk4) {
            float4 xv = xrow[kk4];
            float4 hv = hrow[kk4];
            #pragma unroll
            for (int j = 0; j < 4; ++j) {
                int k = k0 + j;
                float4 wir = *reinterpret_cast<const float4*>(&w_ih[(size_t)(k        ) * D + kk4 * 4]);
                float4 wiz = *reinterpret_cast<const float4*>(&w_ih[(size_t)(k +     D) * D + kk4 * 4]);
                float4 win = *reinterpret_cast<const float4*>(&w_ih[(size_t)(k + 2 * D) * D + kk4 * 4]);
                float4 whr = *reinterpret_cast<const float4*>(&w_hh[(size_t)(k        ) * D + kk4 * 4]);
                float4 whz = *reinterpret_cast<const float4*>(&w_hh[(size_t)(k +     D) * D + kk4 * 4]);
                float4 whn = *reinterpret_cast<const float4*>(&w_hh[(size_t)(k + 2 * D) * D + kk4 * 4]);
                acc[j][0] = dot4(xv, wir, acc[j][0]);
                acc[j][1] = dot4(xv, wiz, acc[j][1]);
                acc[j][2] = dot4(xv, win, acc[j][2]);
                acc[j][3] = dot4(hv, whr, acc[j][3]);
                acc[j][4] = dot4(hv, whz, acc[j][4]);
                acc[j][5] = dot4(hv, whn, acc[j][5]);
            }
        }

        int degn = s_deg[n];
        #pragma unroll
        for (int j = 0; j < 4; ++j) {
            int k = k0 + j;
            float ir = acc[j][0] + b_ih[k];
            float iz = acc[j][1] + b_ih[k + D];
            float in_ = acc[j][2] + b_ih[k + 2 * D];
            float hr = acc[j][3] + b_hh[k];
            float hz = acc[j][4] + b_hh[k + D];
            float hn = acc[j][5] + b_hh[k + 2 * D];
            float r  = sigmoidf_(ir + hr);
            float z  = sigmoidf_(iz + hz);
            float nn = tanhf_(in_ + r * hn);
            float hv_own = s_h[n * XS + k];
            float upd = (1.0f - z) * nn + z * hv_own;
            s_o[n * XS + k] = (degn > 0) ? upd : hv_own;
        }
    }
    __syncthreads();

    // ---- phase 3: coalesced float4 write-out
    for (int idx = tid; idx < NPB * D / 4; idx += 256) {
        int nl = idx >> 5, kk4 = idx & 31;      // D/4 == 32
        int node = base + nl;
        if (node < N) {
            *reinterpret_cast<float4*>(&out[(size_t)node * D + kk4 * 4]) =
                *reinterpret_cast<const float4*>(&s_o[nl * XS + kk4 * 4]);
        }
    }
}

extern "C" void kernel_launch(void* const* d_in, const int* in_sizes, int n_in,
                              void* d_out, int out_size, void* d_ws, size_t ws_size,
                              hipStream_t stream) {
    const int*   src  = (const int*)d_in[0];
    const int*   dst  = (const int*)d_in[1];
    // d_in[2] = t (unused)
    const float* feat = (const float*)d_in[3];
    const float* mem  = (const float*)d_in[4];
    const float* w_ih = (const float*)d_in[5];
    const float* w_hh = (const float*)d_in[6];
    const float* b_ih = (const float*)d_in[7];
    const float* b_hh = (const float*)d_in[8];

    const int E = in_sizes[0];
    const int N = in_sizes[4] / D;
    float* out = (float*)d_out;

    // workspace layout
    char* ws     = (char*)d_ws;
    int*  ticket = (int*)ws;                  // [1] at offset 0
    int*  cnt    = (int*)(ws + 256);          // [N]
    int*  offs   = cnt + N;                   // [N]
    int*  cursor = offs + N;                  // [N]
    int*  nb     = cursor + N;                // [2E]

    // zero ticket + cnt (offs/cursor/nb are fully overwritten each call)
    hipMemsetAsync(ws, 0, 256 + (size_t)N * 4, stream);

    count_kernel  <<<(E + 255) / 256, 256, 0, stream>>>(src, dst, E, cnt);
    offsets_kernel<<<(N + 255) / 256, 256, 0, stream>>>(cnt, N, offs, cursor, ticket);
    fill_kernel   <<<(E + 255) / 256, 256, 0, stream>>>(src, dst, E, cursor, nb);
    gru_kernel    <<<(N + NPB - 1) / NPB, 256, 0, stream>>>(feat, mem, w_ih, w_hh,
                                                            b_ih, b_hh, cnt, offs, nb, out, N);
}

// Round 2
// 763.451 us; speedup vs baseline: 3.7496x; 3.7496x over previous
//
#include <hip/hip_runtime.h>
#include <cstdint>
#include <cstddef>

#define D 128
#define K2 256      // GEMM K dimension = [x | h]
#define NC 512      // GEMM output columns = 4 gates x 128 dims, interleaved per quadrant
#define BM 32       // nodes per block
#define KSTEPS 8    // K2 / 32

typedef __attribute__((ext_vector_type(8))) short bf16x8;
typedef __attribute__((ext_vector_type(4))) float f32x4;

__device__ __forceinline__ unsigned short f2bf(float f) {
    unsigned int u = __float_as_uint(f);
    unsigned int r = (u + 0x7FFFu + ((u >> 16) & 1u)) >> 16;
    return (unsigned short)r;
}

__device__ __forceinline__ float sigmoidf_(float a) {
    return 1.0f / (1.0f + __expf(-a));
}
__device__ __forceinline__ float tanhf_(float a) {
    float e2 = __expf(2.0f * a);
    return 1.0f - 2.0f / (e2 + 1.0f);
}

// ---------------- CSR build (unchanged from R1, proven correct) ----------------
__global__ void count_kernel(const int* __restrict__ src, const int* __restrict__ dst,
                             int E, int* __restrict__ cnt) {
    int m = blockIdx.x * blockDim.x + threadIdx.x;
    if (m < E) {
        atomicAdd(&cnt[src[m]], 1);
        atomicAdd(&cnt[dst[m]], 1);
    }
}

__global__ void offsets_kernel(const int* __restrict__ cnt, int N,
                               int* __restrict__ offs, int* __restrict__ cursor,
                               int* __restrict__ ticket) {
    int i = blockIdx.x * blockDim.x + threadIdx.x;
    int lane = threadIdx.x & 63;
    int c = (i < N) ? cnt[i] : 0;
    int pre = c;
    #pragma unroll
    for (int o = 1; o < 64; o <<= 1) {
        int v = __shfl_up(pre, o);
        if (lane >= o) pre += v;
    }
    int total = __shfl(pre, 63);
    int excl  = pre - c;
    int base = 0;
    if (lane == 0) base = atomicAdd(ticket, total);
    base = __shfl(base, 0);
    if (i < N) {
        offs[i]   = base + excl;
        cursor[i] = base + excl;
    }
}

__global__ void fill_kernel(const int* __restrict__ src, const int* __restrict__ dst,
                            int E, int* __restrict__ cursor, int* __restrict__ nb) {
    int m = blockIdx.x * blockDim.x + threadIdx.x;
    if (m < E) {
        int s = src[m], d = dst[m];
        int p1 = atomicAdd(&cursor[s], 1); nb[p1] = d;
        int p2 = atomicAdd(&cursor[d], 1); nb[p2] = s;
    }
}

// ---------------- B-matrix prep: bf16 [8 ksteps][512 cols][32 kin] ----------------
// Logical B[K][col], K in [0,256): K<128 -> x part (w_ih), K>=128 -> h part (w_hh).
// col -> (q = col>>7, gate = (col>>5)&3, d = (col&31) + q*32), output dim d, gates:
//   0: r_sum (both), 1: z_sum (both), 2: i_n (x only), 3: h_n (h only)
__global__ void prep_b(const float* __restrict__ w_ih, const float* __restrict__ w_hh,
                       unsigned short* __restrict__ Bp) {
    int idx = blockIdx.x * 256 + threadIdx.x;    // 131072 total
    int kin   = idx & 31;
    int col   = (idx >> 5) & 511;
    int kstep = idx >> 14;
    int K = kstep * 32 + kin;
    int q = col >> 7, gate = (col >> 5) & 3, d = (col & 31) + q * 32;
    float v = 0.0f;
    if (K < 128) {
        if (gate < 3) v = w_ih[(gate * 128 + d) * 128 + K];
    } else {
        int kh = K - 128;
        if (gate == 0)      v = w_hh[(d) * 128 + kh];
        else if (gate == 1) v = w_hh[(128 + d) * 128 + kh];
        else if (gate == 3) v = w_hh[(256 + d) * 128 + kh];
    }
    Bp[idx] = f2bf(v);
}

// ---------------- fused gather + bf16 MFMA GEMM + GRU epilogue ----------------
// 256 threads = 4 waves. Block tile: 32 nodes x 512 cols. Wave w handles col
// quadrant w*128 (= dims w*32..w*32+31, all 4 gates). A[32][256] bf16 in LDS,
// XOR-swizzled (elem k stored at k ^ ((row&7)<<3)) -> conflict-free ds_read_b128.
__global__ __launch_bounds__(256) void gru_mfma(
    const float* __restrict__ feat, const float* __restrict__ mem,
    const unsigned short* __restrict__ Bp,
    const float* __restrict__ b_ih, const float* __restrict__ b_hh,
    const int* __restrict__ cnt, const int* __restrict__ offs,
    const int* __restrict__ nb, float* __restrict__ out, int N)
{
    __shared__ unsigned short A_lds[BM * K2];   // 16 KB
    __shared__ int s_deg[BM];

    const int tid  = threadIdx.x;
    const int lane = tid & 63;
    const int wid  = tid >> 6;          // 0..3
    const int base = blockIdx.x * BM;

    // ---- stage h (memory rows) -> A_lds[k = 128..255], bf16, swizzled
    for (int idx = tid; idx < BM * 32; idx += 256) {
        int r = idx >> 5, c4 = idx & 31;
        float4 hv = *reinterpret_cast<const float4*>(&mem[(size_t)(base + r) * D + c4 * 4]);
        unsigned int lo = (unsigned int)f2bf(hv.x) | ((unsigned int)f2bf(hv.y) << 16);
        unsigned int hi = (unsigned int)f2bf(hv.z) | ((unsigned int)f2bf(hv.w) << 16);
        uint2 pk = {lo, hi};
        int eb = (128 + c4 * 4) ^ ((r & 7) << 3);
        *reinterpret_cast<uint2*>(&A_lds[r * K2 + eb]) = pk;
    }

    // ---- gather-mean neighbor features -> A_lds[k = 0..127], bf16, swizzled
    for (int q = 0; q < BM / 4; ++q) {
        int nl = wid * (BM / 4) + q;
        int node = base + nl;
        int deg = cnt[node];
        int off = offs[node];
        float2 a0 = {0.0f, 0.0f}, a1 = {0.0f, 0.0f};
        int e = 0;
        for (; e + 1 < deg; e += 2) {          // 2-edge unroll for load ILP
            int n0 = nb[off + e], n1 = nb[off + e + 1];
            float2 f0 = *reinterpret_cast<const float2*>(&feat[(size_t)n0 * D + lane * 2]);
            float2 f1 = *reinterpret_cast<const float2*>(&feat[(size_t)n1 * D + lane * 2]);
            a0.x += f0.x; a0.y += f0.y;
            a1.x += f1.x; a1.y += f1.y;
        }
        if (e < deg) {
            int n0 = nb[off + e];
            float2 f0 = *reinterpret_cast<const float2*>(&feat[(size_t)n0 * D + lane * 2]);
            a0.x += f0.x; a0.y += f0.y;
        }
        float inv = 1.0f / (float)(deg > 0 ? deg : 1);
        float mx = (a0.x + a1.x) * inv;
        float my = (a0.y + a1.y) * inv;
        int eb = (lane * 2) ^ ((nl & 7) << 3);
        unsigned int pk = (unsigned int)f2bf(mx) | ((unsigned int)f2bf(my) << 16);
        *reinterpret_cast<unsigned int*>(&A_lds[nl * K2 + eb]) = pk;
        if (lane == 0) s_deg[nl] = deg;
    }
    __syncthreads();

    // ---- MFMA GEMM: 32 x 128(quadrant) x 256, A from LDS, B frags from global (L2)
    f32x4 acc[2][8];
    #pragma unroll
    for (int m = 0; m < 2; ++m)
        #pragma unroll
        for (int f = 0; f < 8; ++f)
            acc[m][f] = (f32x4){0.0f, 0.0f, 0.0f, 0.0f};

    const int r0 = lane & 15;
    const int r1 = 16 + (lane & 15);
    const int kgrp = (lane >> 4) * 8;

    #pragma unroll
    for (int ks = 0; ks < KSTEPS; ++ks) {
        int kb = ks * 32 + kgrp;
        bf16x8 a0 = *reinterpret_cast<const bf16x8*>(&A_lds[r0 * K2 + (kb ^ ((r0 & 7) << 3))]);
        bf16x8 a1 = *reinterpret_cast<const bf16x8*>(&A_lds[r1 * K2 + (kb ^ ((r1 & 7) << 3))]);
        #pragma unroll
        for (int f = 0; f < 8; ++f) {
            int col = wid * 128 + f * 16 + (lane & 15);
            bf16x8 bfr = *reinterpret_cast<const bf16x8*>(&Bp[((ks * 512 + col) << 5) + kgrp]);
            acc[0][f] = __builtin_amdgcn_mfma_f32_16x16x32_bf16(a0, bfr, acc[0][f], 0, 0, 0);
            acc[1][f] = __builtin_amdgcn_mfma_f32_16x16x32_bf16(a1, bfr, acc[1][f], 0, 0, 0);
        }
    }

    // ---- fused GRU epilogue. C/D frag: col = lane&15, row = (lane>>4)*4 + j.
    #pragma unroll
    for (int m = 0; m < 2; ++m) {
        #pragma unroll
        for (int dh = 0; dh < 2; ++dh) {
            f32x4 ar = acc[m][0 * 2 + dh];
            f32x4 az = acc[m][1 * 2 + dh];
            f32x4 an = acc[m][2 * 2 + dh];
            f32x4 ah = acc[m][3 * 2 + dh];
            int d = wid * 32 + dh * 16 + (lane & 15);
            float br = b_ih[d]       + b_hh[d];
            float bz = b_ih[128 + d] + b_hh[128 + d];
            float bi = b_ih[256 + d];
            float bh = b_hh[256 + d];
            #pragma unroll
            for (int j = 0; j < 4; ++j) {
                int rloc = m * 16 + (lane >> 4) * 4 + j;
                int node = base + rloc;
                float h  = mem[(size_t)node * D + d];
                float rv = sigmoidf_(ar[j] + br);
                float zv = sigmoidf_(az[j] + bz);
                float nv = tanhf_(an[j] + bi + rv * (ah[j] + bh));
                float o  = (s_deg[rloc] > 0) ? ((1.0f - zv) * nv + zv * h) : h;
                out[(size_t)node * D + d] = o;
            }
        }
    }
}

extern "C" void kernel_launch(void* const* d_in, const int* in_sizes, int n_in,
                              void* d_out, int out_size, void* d_ws, size_t ws_size,
                              hipStream_t stream) {
    const int*   src  = (const int*)d_in[0];
    const int*   dst  = (const int*)d_in[1];
    const float* feat = (const float*)d_in[3];
    const float* mem  = (const float*)d_in[4];
    const float* w_ih = (const float*)d_in[5];
    const float* w_hh = (const float*)d_in[6];
    const float* b_ih = (const float*)d_in[7];
    const float* b_hh = (const float*)d_in[8];

    const int E = in_sizes[0];
    const int N = in_sizes[4] / D;
    float* out = (float*)d_out;

    // workspace layout
    char* ws     = (char*)d_ws;
    int*  ticket = (int*)ws;                  // [1]
    int*  cnt    = (int*)(ws + 256);          // [N]
    int*  offs   = cnt + N;                   // [N]
    int*  cursor = offs + N;                  // [N]
    int*  nb     = cursor + N;                // [2E]
    size_t boff  = ((256 + 3 * (size_t)N * 4 + 2 * (size_t)E * 4) + 255) & ~(size_t)255;
    unsigned short* Bp = (unsigned short*)(ws + boff);   // [8*512*32] bf16 = 256 KB

    hipMemsetAsync(ws, 0, 256 + (size_t)N * 4, stream);

    count_kernel  <<<(E + 255) / 256, 256, 0, stream>>>(src, dst, E, cnt);
    offsets_kernel<<<(N + 255) / 256, 256, 0, stream>>>(cnt, N, offs, cursor, ticket);
    fill_kernel   <<<(E + 255) / 256, 256, 0, stream>>>(src, dst, E, cursor, nb);
    prep_b        <<<512, 256, 0, stream>>>(w_ih, w_hh, Bp);
    gru_mfma      <<<(N + BM - 1) / BM, 256, 0, stream>>>(feat, mem, Bp, b_ih, b_hh,
                                                          cnt, offs, nb, out, N);
}

// Round 3
// 598.739 us; speedup vs baseline: 4.7811x; 1.2751x over previous
//
#include <hip/hip_runtime.h>
#include <cstdint>
#include <cstddef>

#define D 128
#define K2 256      // GEMM K dimension = [x | h]
#define BM 64       // nodes per block in GEMM
#define KSTEPS 8    // K2 / 32

typedef __attribute__((ext_vector_type(8))) short bf16x8;
typedef __attribute__((ext_vector_type(4))) float f32x4;

__device__ __forceinline__ unsigned short f2bf(float f) {
    unsigned int u = __float_as_uint(f);
    unsigned int r = (u + 0x7FFFu + ((u >> 16) & 1u)) >> 16;
    return (unsigned short)r;
}

__device__ __forceinline__ float sigmoidf_(float a) {
    return 1.0f / (1.0f + __expf(-a));
}
__device__ __forceinline__ float tanhf_(float a) {
    float e2 = __expf(2.0f * a);
    return 1.0f - 2.0f / (e2 + 1.0f);
}

// ---------------- CSR build ----------------
__global__ void count_kernel(const int* __restrict__ src, const int* __restrict__ dst,
                             int E, int* __restrict__ cnt) {
    int m = blockIdx.x * blockDim.x + threadIdx.x;
    if (m < E) {
        atomicAdd(&cnt[src[m]], 1);
        atomicAdd(&cnt[dst[m]], 1);
    }
}

__global__ void offsets_kernel(const int* __restrict__ cnt, int N,
                               int* __restrict__ offs, int* __restrict__ cursor,
                               int* __restrict__ ticket) {
    int i = blockIdx.x * blockDim.x + threadIdx.x;
    int lane = threadIdx.x & 63;
    int c = (i < N) ? cnt[i] : 0;
    int pre = c;
    #pragma unroll
    for (int o = 1; o < 64; o <<= 1) {
        int v = __shfl_up(pre, o);
        if (lane >= o) pre += v;
    }
    int total = __shfl(pre, 63);
    int excl  = pre - c;
    int base = 0;
    if (lane == 0) base = atomicAdd(ticket, total);
    base = __shfl(base, 0);
    if (i < N) {
        offs[i]   = base + excl;
        cursor[i] = base + excl;
    }
}

__global__ void fill_kernel(const int* __restrict__ src, const int* __restrict__ dst,
                            int E, int* __restrict__ cursor, int* __restrict__ nb) {
    int m = blockIdx.x * blockDim.x + threadIdx.x;
    if (m < E) {
        int s = src[m], d = dst[m];
        int p1 = atomicAdd(&cursor[s], 1); nb[p1] = d;
        int p2 = atomicAdd(&cursor[d], 1); nb[p2] = s;
    }
}

// ---------------- gather-mean: one wave per node, 8 edges in flight ----------------
// lane layout: half = lane>>5 selects one of 2 edges per load instr,
// (lane&31)*4 selects float4 column -> 32 lanes x 16B = full 512B row.
__global__ __launch_bounds__(256) void gather_kernel(
    const float* __restrict__ feat, const int* __restrict__ cnt,
    const int* __restrict__ offs, const int* __restrict__ nb,
    unsigned short* __restrict__ agg, int N)
{
    int node = blockIdx.x * 4 + (threadIdx.x >> 6);
    if (node >= N) return;
    const int lane = threadIdx.x & 63;
    const int half = lane >> 5;
    const int col  = (lane & 31) * 4;

    int deg = cnt[node];
    int off = offs[node];

    float4 a0 = {0,0,0,0}, a1 = {0,0,0,0}, a2 = {0,0,0,0}, a3 = {0,0,0,0};
    int e = 0;
    for (; e + 8 <= deg; e += 8) {
        int i0 = nb[off + e + 0 + half];
        int i1 = nb[off + e + 2 + half];
        int i2 = nb[off + e + 4 + half];
        int i3 = nb[off + e + 6 + half];
        float4 f0 = *reinterpret_cast<const float4*>(&feat[(size_t)i0 * D + col]);
        float4 f1 = *reinterpret_cast<const float4*>(&feat[(size_t)i1 * D + col]);
        float4 f2 = *reinterpret_cast<const float4*>(&feat[(size_t)i2 * D + col]);
        float4 f3 = *reinterpret_cast<const float4*>(&feat[(size_t)i3 * D + col]);
        a0.x += f0.x; a0.y += f0.y; a0.z += f0.z; a0.w += f0.w;
        a1.x += f1.x; a1.y += f1.y; a1.z += f1.z; a1.w += f1.w;
        a2.x += f2.x; a2.y += f2.y; a2.z += f2.z; a2.w += f2.w;
        a3.x += f3.x; a3.y += f3.y; a3.z += f3.z; a3.w += f3.w;
    }
    for (; e + 2 <= deg; e += 2) {
        int i0 = nb[off + e + half];
        float4 f0 = *reinterpret_cast<const float4*>(&feat[(size_t)i0 * D + col]);
        a0.x += f0.x; a0.y += f0.y; a0.z += f0.z; a0.w += f0.w;
    }
    if (e < deg && half == 0) {
        int i0 = nb[off + e];
        float4 f0 = *reinterpret_cast<const float4*>(&feat[(size_t)i0 * D + col]);
        a1.x += f0.x; a1.y += f0.y; a1.z += f0.z; a1.w += f0.w;
    }
    float sx = a0.x + a1.x + a2.x + a3.x;
    float sy = a0.y + a1.y + a2.y + a3.y;
    float sz = a0.z + a1.z + a2.z + a3.z;
    float sw = a0.w + a1.w + a2.w + a3.w;
    sx += __shfl_xor(sx, 32);
    sy += __shfl_xor(sy, 32);
    sz += __shfl_xor(sz, 32);
    sw += __shfl_xor(sw, 32);
    if (half == 0) {
        float inv = (deg > 0) ? 1.0f / (float)deg : 0.0f;
        unsigned int lo = (unsigned int)f2bf(sx * inv) | ((unsigned int)f2bf(sy * inv) << 16);
        unsigned int hi = (unsigned int)f2bf(sz * inv) | ((unsigned int)f2bf(sw * inv) << 16);
        uint2 pk = {lo, hi};
        *reinterpret_cast<uint2*>(&agg[(size_t)node * D + col]) = pk;
    }
}

// ---------------- B-matrix prep (unchanged) ----------------
__global__ void prep_b(const float* __restrict__ w_ih, const float* __restrict__ w_hh,
                       unsigned short* __restrict__ Bp) {
    int idx = blockIdx.x * 256 + threadIdx.x;    // 131072 total
    int kin   = idx & 31;
    int col   = (idx >> 5) & 511;
    int kstep = idx >> 14;
    int K = kstep * 32 + kin;
    int q = col >> 7, gate = (col >> 5) & 3, d = (col & 31) + q * 32;
    float v = 0.0f;
    if (K < 128) {
        if (gate < 3) v = w_ih[(gate * 128 + d) * 128 + K];
    } else {
        int kh = K - 128;
        if (gate == 0)      v = w_hh[(d) * 128 + kh];
        else if (gate == 1) v = w_hh[(128 + d) * 128 + kh];
        else if (gate == 3) v = w_hh[(256 + d) * 128 + kh];
    }
    Bp[idx] = f2bf(v);
}

// ---------------- bf16 MFMA GEMM + fused GRU epilogue ----------------
// 512 threads = 8 waves. Tile: 64 nodes x 512 cols. Wave w: row-half mh=w>>2
// (rows mh*32..+31), col quadrant q=w&3 (dims q*32..+31, all 4 gates).
__global__ __launch_bounds__(512) void gru_gemm(
    const unsigned short* __restrict__ agg, const float* __restrict__ mem,
    const unsigned short* __restrict__ Bp,
    const float* __restrict__ b_ih, const float* __restrict__ b_hh,
    const int* __restrict__ cnt, float* __restrict__ out, int N)
{
    __shared__ unsigned short A_lds[BM * K2];   // 32 KB
    __shared__ int s_deg[BM];

    const int tid  = threadIdx.x;
    const int lane = tid & 63;
    const int wid  = tid >> 6;          // 0..7
    const int base = blockIdx.x * BM;

    // stage x (agg, bf16, coalesced 16B) -> A_lds[k=0..127], swizzled
    for (int idx = tid; idx < BM * 16; idx += 512) {
        int r = idx >> 4, c8 = idx & 15;
        uint4 v = reinterpret_cast<const uint4*>(agg)[(size_t)(base + r) * 16 + c8];
        int eb = (c8 * 8) ^ ((r & 7) << 3);
        *reinterpret_cast<uint4*>(&A_lds[r * K2 + eb]) = v;
    }
    // stage h (mem, fp32 -> bf16) -> A_lds[k=128..255], swizzled
    for (int idx = tid; idx < BM * 32; idx += 512) {
        int r = idx >> 5, c4 = idx & 31;
        float4 hv = *reinterpret_cast<const float4*>(&mem[(size_t)(base + r) * D + c4 * 4]);
        unsigned int lo = (unsigned int)f2bf(hv.x) | ((unsigned int)f2bf(hv.y) << 16);
        unsigned int hi = (unsigned int)f2bf(hv.z) | ((unsigned int)f2bf(hv.w) << 16);
        uint2 pk = {lo, hi};
        int eb = (128 + c4 * 4) ^ ((r & 7) << 3);
        *reinterpret_cast<uint2*>(&A_lds[r * K2 + eb]) = pk;
    }
    if (tid < BM) s_deg[tid] = cnt[base + tid];
    __syncthreads();

    const int mh = wid >> 2;            // row half: 0/1
    const int q  = wid & 3;             // col quadrant

    f32x4 acc[2][8];
    #pragma unroll
    for (int m = 0; m < 2; ++m)
        #pragma unroll
        for (int f = 0; f < 8; ++f)
            acc[m][f] = (f32x4){0.0f, 0.0f, 0.0f, 0.0f};

    const int r0 = mh * 32 + (lane & 15);
    const int r1 = r0 + 16;
    const int kgrp = (lane >> 4) * 8;

    #pragma unroll
    for (int ks = 0; ks < KSTEPS; ++ks) {
        int kb = ks * 32 + kgrp;
        bf16x8 a0 = *reinterpret_cast<const bf16x8*>(&A_lds[r0 * K2 + (kb ^ ((r0 & 7) << 3))]);
        bf16x8 a1 = *reinterpret_cast<const bf16x8*>(&A_lds[r1 * K2 + (kb ^ ((r1 & 7) << 3))]);
        #pragma unroll
        for (int f = 0; f < 8; ++f) {
            int col = q * 128 + f * 16 + (lane & 15);
            bf16x8 bfr = *reinterpret_cast<const bf16x8*>(&Bp[((ks * 512 + col) << 5) + kgrp]);
            acc[0][f] = __builtin_amdgcn_mfma_f32_16x16x32_bf16(a0, bfr, acc[0][f], 0, 0, 0);
            acc[1][f] = __builtin_amdgcn_mfma_f32_16x16x32_bf16(a1, bfr, acc[1][f], 0, 0, 0);
        }
    }

    // fused GRU epilogue. C/D frag: col = lane&15, row = (lane>>4)*4 + j.
    #pragma unroll
    for (int m = 0; m < 2; ++m) {
        #pragma unroll
        for (int dh = 0; dh < 2; ++dh) {
            f32x4 ar = acc[m][0 * 2 + dh];
            f32x4 az = acc[m][1 * 2 + dh];
            f32x4 an = acc[m][2 * 2 + dh];
            f32x4 ah = acc[m][3 * 2 + dh];
            int d = q * 32 + dh * 16 + (lane & 15);
            float br = b_ih[d]       + b_hh[d];
            float bz = b_ih[128 + d] + b_hh[128 + d];
            float bi = b_ih[256 + d];
            float bh = b_hh[256 + d];
            #pragma unroll
            for (int j = 0; j < 4; ++j) {
                int rloc = mh * 32 + m * 16 + (lane >> 4) * 4 + j;
                int node = base + rloc;
                float h  = mem[(size_t)node * D + d];
                float rv = sigmoidf_(ar[j] + br);
                float zv = sigmoidf_(az[j] + bz);
                float nv = tanhf_(an[j] + bi + rv * (ah[j] + bh));
                float o  = (s_deg[rloc] > 0) ? ((1.0f - zv) * nv + zv * h) : h;
                out[(size_t)node * D + d] = o;
            }
        }
    }
}

extern "C" void kernel_launch(void* const* d_in, const int* in_sizes, int n_in,
                              void* d_out, int out_size, void* d_ws, size_t ws_size,
                              hipStream_t stream) {
    const int*   src  = (const int*)d_in[0];
    const int*   dst  = (const int*)d_in[1];
    const float* feat = (const float*)d_in[3];
    const float* mem  = (const float*)d_in[4];
    const float* w_ih = (const float*)d_in[5];
    const float* w_hh = (const float*)d_in[6];
    const float* b_ih = (const float*)d_in[7];
    const float* b_hh = (const float*)d_in[8];

    const int E = in_sizes[0];
    const int N = in_sizes[4] / D;
    float* out = (float*)d_out;

    // workspace layout
    char* ws     = (char*)d_ws;
    int*  ticket = (int*)ws;                  // [1]
    int*  cnt    = (int*)(ws + 256);          // [N]
    int*  offs   = cnt + N;                   // [N]
    int*  cursor = offs + N;                  // [N]
    int*  nb     = cursor + N;                // [2E]
    size_t boff  = ((256 + 3 * (size_t)N * 4 + 2 * (size_t)E * 4) + 255) & ~(size_t)255;
    unsigned short* Bp  = (unsigned short*)(ws + boff);          // 256 KB
    unsigned short* agg = (unsigned short*)(ws + boff + 262144); // [N*D] bf16 = 51.2 MB

    hipMemsetAsync(ws, 0, 256 + (size_t)N * 4, stream);

    count_kernel  <<<(E + 255) / 256, 256, 0, stream>>>(src, dst, E, cnt);
    offsets_kernel<<<(N + 255) / 256, 256, 0, stream>>>(cnt, N, offs, cursor, ticket);
    fill_kernel   <<<(E + 255) / 256, 256, 0, stream>>>(src, dst, E, cursor, nb);
    gather_kernel <<<(N + 3) / 4, 256, 0, stream>>>(feat, cnt, offs, nb, agg, N);
    prep_b        <<<512, 256, 0, stream>>>(w_ih, w_hh, Bp);
    gru_gemm      <<<N / BM, 512, 0, stream>>>(agg, mem, Bp, b_ih, b_hh, cnt, out, N);
}

// Round 6
// 553.193 us; speedup vs baseline: 5.1747x; 1.0823x over previous
//
#include <hip/hip_runtime.h>
#include <cstdint>
#include <cstddef>

#define D 128
#define K2 256      // GEMM K dimension = [x | h]
#define BM 64       // nodes per block in GEMM
#define KSTEPS 8    // K2 / 32

typedef __attribute__((ext_vector_type(8))) short bf16x8;
typedef __attribute__((ext_vector_type(4))) float f32x4;

__device__ __forceinline__ unsigned short f2bf(float f) {
    unsigned int u = __float_as_uint(f);
    unsigned int r = (u + 0x7FFFu + ((u >> 16) & 1u)) >> 16;
    return (unsigned short)r;
}

__device__ __forceinline__ float sigmoidf_(float a) {
    return 1.0f / (1.0f + __expf(-a));
}
__device__ __forceinline__ float tanhf_(float a) {
    float e2 = __expf(2.0f * a);
    return 1.0f - 2.0f / (e2 + 1.0f);
}

// ---------------- CSR build: 4 edges/thread for 8 atomics in flight ----------------
// NOTE: threads t >= T MUST be masked out — edge m = t + j*T with t in
// [T, gridSize) aliases edge handled by thread t-T at j+1 (R4/R5 bug).
__global__ void count_kernel(const int* __restrict__ src, const int* __restrict__ dst,
                             int E, int T, int* __restrict__ cnt) {
    int t = blockIdx.x * blockDim.x + threadIdx.x;
    if (t >= T) return;
    #pragma unroll
    for (int j = 0; j < 4; ++j) {
        int m = t + j * T;
        if (m < E) {
            atomicAdd(&cnt[src[m]], 1);
            atomicAdd(&cnt[dst[m]], 1);
        }
    }
}

__global__ void offsets_kernel(const int* __restrict__ cnt, int N,
                               int* __restrict__ offs, int* __restrict__ cursor,
                               int* __restrict__ ticket) {
    int i = blockIdx.x * blockDim.x + threadIdx.x;
    int lane = threadIdx.x & 63;
    int c = (i < N) ? cnt[i] : 0;
    int pre = c;
    #pragma unroll
    for (int o = 1; o < 64; o <<= 1) {
        int v = __shfl_up(pre, o);
        if (lane >= o) pre += v;
    }
    int total = __shfl(pre, 63);
    int excl  = pre - c;
    int base = 0;
    if (lane == 0) base = atomicAdd(ticket, total);
    base = __shfl(base, 0);
    if (i < N) {
        offs[i]   = base + excl;
        cursor[i] = base + excl;
    }
}

__global__ void fill_kernel(const int* __restrict__ src, const int* __restrict__ dst,
                            int E, int T, int* __restrict__ cursor, int* __restrict__ nb) {
    int t = blockIdx.x * blockDim.x + threadIdx.x;
    if (t >= T) return;
    int s[4], d[4], p0[4], p1[4];
    bool v[4];
    #pragma unroll
    for (int j = 0; j < 4; ++j) {
        int m = t + j * T;
        v[j] = (m < E);
        if (v[j]) { s[j] = src[m]; d[j] = dst[m]; }
    }
    #pragma unroll
    for (int j = 0; j < 4; ++j) {
        if (v[j]) {
            p0[j] = atomicAdd(&cursor[s[j]], 1);
            p1[j] = atomicAdd(&cursor[d[j]], 1);
        }
    }
    #pragma unroll
    for (int j = 0; j < 4; ++j) {
        if (v[j]) {
            nb[p0[j]] = d[j];
            nb[p1[j]] = s[j];
        }
    }
}

// ---------------- gather-mean over fp32 rows: one wave/node, 8 loads in flight ----------------
__global__ __launch_bounds__(256) void gather_f32(
    const float* __restrict__ feat, const int* __restrict__ cnt,
    const int* __restrict__ offs, const int* __restrict__ nb,
    unsigned short* __restrict__ agg, int N)
{
    int node = blockIdx.x * 4 + (threadIdx.x >> 6);
    if (node >= N) return;
    const int lane = threadIdx.x & 63;
    const int half = lane >> 5;
    const int col  = (lane & 31) * 4;

    int deg = cnt[node];
    int off = offs[node];

    float4 a0 = {0,0,0,0}, a1 = {0,0,0,0}, a2 = {0,0,0,0}, a3 = {0,0,0,0};
    int e = 0;
    for (; e + 8 <= deg; e += 8) {
        int i0 = nb[off + e + 0 + half];
        int i1 = nb[off + e + 2 + half];
        int i2 = nb[off + e + 4 + half];
        int i3 = nb[off + e + 6 + half];
        float4 f0 = *reinterpret_cast<const float4*>(&feat[(size_t)i0 * D + col]);
        float4 f1 = *reinterpret_cast<const float4*>(&feat[(size_t)i1 * D + col]);
        float4 f2 = *reinterpret_cast<const float4*>(&feat[(size_t)i2 * D + col]);
        float4 f3 = *reinterpret_cast<const float4*>(&feat[(size_t)i3 * D + col]);
        a0.x += f0.x; a0.y += f0.y; a0.z += f0.z; a0.w += f0.w;
        a1.x += f1.x; a1.y += f1.y; a1.z += f1.z; a1.w += f1.w;
        a2.x += f2.x; a2.y += f2.y; a2.z += f2.z; a2.w += f2.w;
        a3.x += f3.x; a3.y += f3.y; a3.z += f3.z; a3.w += f3.w;
    }
    for (; e + 2 <= deg; e += 2) {
        int i0 = nb[off + e + half];
        float4 f0 = *reinterpret_cast<const float4*>(&feat[(size_t)i0 * D + col]);
        a0.x += f0.x; a0.y += f0.y; a0.z += f0.z; a0.w += f0.w;
    }
    if (e < deg && half == 0) {
        int i0 = nb[off + e];
        float4 f0 = *reinterpret_cast<const float4*>(&feat[(size_t)i0 * D + col]);
        a1.x += f0.x; a1.y += f0.y; a1.z += f0.z; a1.w += f0.w;
    }
    float sx = a0.x + a1.x + a2.x + a3.x;
    float sy = a0.y + a1.y + a2.y + a3.y;
    float sz = a0.z + a1.z + a2.z + a3.z;
    float sw = a0.w + a1.w + a2.w + a3.w;
    sx += __shfl_xor(sx, 32);
    sy += __shfl_xor(sy, 32);
    sz += __shfl_xor(sz, 32);
    sw += __shfl_xor(sw, 32);
    if (half == 0) {
        float inv = (deg > 0) ? 1.0f / (float)deg : 0.0f;
        unsigned int lo = (unsigned int)f2bf(sx * inv) | ((unsigned int)f2bf(sy * inv) << 16);
        unsigned int hi = (unsigned int)f2bf(sz * inv) | ((unsigned int)f2bf(sw * inv) << 16);
        uint2 pk = {lo, hi};
        *reinterpret_cast<uint2*>(&agg[(size_t)node * D + col]) = pk;
    }
}

// ---------------- B-matrix prep ----------------
__global__ void prep_b(const float* __restrict__ w_ih, const float* __restrict__ w_hh,
                       unsigned short* __restrict__ Bp) {
    int idx = blockIdx.x * 256 + threadIdx.x;    // 131072 total
    int kin   = idx & 31;
    int col   = (idx >> 5) & 511;
    int kstep = idx >> 14;
    int K = kstep * 32 + kin;
    int q = col >> 7, gate = (col >> 5) & 3, d = (col & 31) + q * 32;
    float v = 0.0f;
    if (K < 128) {
        if (gate < 3) v = w_ih[(gate * 128 + d) * 128 + K];
    } else {
        int kh = K - 128;
        if (gate == 0)      v = w_hh[(d) * 128 + kh];
        else if (gate == 1) v = w_hh[(128 + d) * 128 + kh];
        else if (gate == 3) v = w_hh[(256 + d) * 128 + kh];
    }
    Bp[idx] = f2bf(v);
}

// ---------------- bf16 MFMA GEMM + fused GRU epilogue ----------------
__global__ __launch_bounds__(512) void gru_gemm(
    const unsigned short* __restrict__ agg, const float* __restrict__ mem,
    const unsigned short* __restrict__ Bp,
    const float* __restrict__ b_ih, const float* __restrict__ b_hh,
    const int* __restrict__ cnt, float* __restrict__ out, int N)
{
    __shared__ unsigned short A_lds[BM * K2];   // 32 KB
    __shared__ int s_deg[BM];

    const int tid  = threadIdx.x;
    const int lane = tid & 63;
    const int wid  = tid >> 6;          // 0..7
    const int base = blockIdx.x * BM;

    for (int idx = tid; idx < BM * 16; idx += 512) {
        int r = idx >> 4, c8 = idx & 15;
        uint4 v = reinterpret_cast<const uint4*>(agg)[(size_t)(base + r) * 16 + c8];
        int eb = (c8 * 8) ^ ((r & 7) << 3);
        *reinterpret_cast<uint4*>(&A_lds[r * K2 + eb]) = v;
    }
    for (int idx = tid; idx < BM * 32; idx += 512) {
        int r = idx >> 5, c4 = idx & 31;
        float4 hv = *reinterpret_cast<const float4*>(&mem[(size_t)(base + r) * D + c4 * 4]);
        unsigned int lo = (unsigned int)f2bf(hv.x) | ((unsigned int)f2bf(hv.y) << 16);
        unsigned int hi = (unsigned int)f2bf(hv.z) | ((unsigned int)f2bf(hv.w) << 16);
        uint2 pk = {lo, hi};
        int eb = (128 + c4 * 4) ^ ((r & 7) << 3);
        *reinterpret_cast<uint2*>(&A_lds[r * K2 + eb]) = pk;
    }
    if (tid < BM) s_deg[tid] = cnt[base + tid];
    __syncthreads();

    const int mh = wid >> 2;
    const int q  = wid & 3;

    f32x4 acc[2][8];
    #pragma unroll
    for (int m = 0; m < 2; ++m)
        #pragma unroll
        for (int f = 0; f < 8; ++f)
            acc[m][f] = (f32x4){0.0f, 0.0f, 0.0f, 0.0f};

    const int r0 = mh * 32 + (lane & 15);
    const int r1 = r0 + 16;
    const int kgrp = (lane >> 4) * 8;

    #pragma unroll
    for (int ks = 0; ks < KSTEPS; ++ks) {
        int kb = ks * 32 + kgrp;
        bf16x8 a0 = *reinterpret_cast<const bf16x8*>(&A_lds[r0 * K2 + (kb ^ ((r0 & 7) << 3))]);
        bf16x8 a1 = *reinterpret_cast<const bf16x8*>(&A_lds[r1 * K2 + (kb ^ ((r1 & 7) << 3))]);
        #pragma unroll
        for (int f = 0; f < 8; ++f) {
            int col = q * 128 + f * 16 + (lane & 15);
            bf16x8 bfr = *reinterpret_cast<const bf16x8*>(&Bp[((ks * 512 + col) << 5) + kgrp]);
            acc[0][f] = __builtin_amdgcn_mfma_f32_16x16x32_bf16(a0, bfr, acc[0][f], 0, 0, 0);
            acc[1][f] = __builtin_amdgcn_mfma_f32_16x16x32_bf16(a1, bfr, acc[1][f], 0, 0, 0);
        }
    }

    #pragma unroll
    for (int m = 0; m < 2; ++m) {
        #pragma unroll
        for (int dh = 0; dh < 2; ++dh) {
            f32x4 ar = acc[m][0 * 2 + dh];
            f32x4 az = acc[m][1 * 2 + dh];
            f32x4 an = acc[m][2 * 2 + dh];
            f32x4 ah = acc[m][3 * 2 + dh];
            int d = q * 32 + dh * 16 + (lane & 15);
            float br = b_ih[d]       + b_hh[d];
            float bz = b_ih[128 + d] + b_hh[128 + d];
            float bi = b_ih[256 + d];
            float bh = b_hh[256 + d];
            #pragma unroll
            for (int j = 0; j < 4; ++j) {
                int rloc = mh * 32 + m * 16 + (lane >> 4) * 4 + j;
                int node = base + rloc;
                float h  = mem[(size_t)node * D + d];
                float rv = sigmoidf_(ar[j] + br);
                float zv = sigmoidf_(az[j] + bz);
                float nv = tanhf_(an[j] + bi + rv * (ah[j] + bh));
                float o  = (s_deg[rloc] > 0) ? ((1.0f - zv) * nv + zv * h) : h;
                out[(size_t)node * D + d] = o;
            }
        }
    }
}

extern "C" void kernel_launch(void* const* d_in, const int* in_sizes, int n_in,
                              void* d_out, int out_size, void* d_ws, size_t ws_size,
                              hipStream_t stream) {
    const int*   src  = (const int*)d_in[0];
    const int*   dst  = (const int*)d_in[1];
    const float* feat = (const float*)d_in[3];
    const float* mem  = (const float*)d_in[4];
    const float* w_ih = (const float*)d_in[5];
    const float* w_hh = (const float*)d_in[6];
    const float* b_ih = (const float*)d_in[7];
    const float* b_hh = (const float*)d_in[8];

    const int E = in_sizes[0];
    const int N = in_sizes[4] / D;
    float* out = (float*)d_out;

    // workspace layout
    char* ws     = (char*)d_ws;
    int*  ticket = (int*)ws;                  // [1]
    int*  cnt    = (int*)(ws + 256);          // [N]
    int*  offs   = cnt + N;                   // [N]
    int*  cursor = offs + N;                  // [N]
    int*  nb     = cursor + N;                // [2E]
    size_t boff  = ((256 + 3 * (size_t)N * 4 + 2 * (size_t)E * 4) + 255) & ~(size_t)255;
    unsigned short* Bp  = (unsigned short*)(ws + boff);          // 256 KB
    unsigned short* agg = (unsigned short*)(ws + boff + 262144); // [N*D] bf16

    hipMemsetAsync(ws, 0, 256 + (size_t)N * 4, stream);

    const int T = (E + 3) / 4;
    count_kernel  <<<(T + 255) / 256, 256, 0, stream>>>(src, dst, E, T, cnt);
    offsets_kernel<<<(N + 255) / 256, 256, 0, stream>>>(cnt, N, offs, cursor, ticket);
    fill_kernel   <<<(T + 255) / 256, 256, 0, stream>>>(src, dst, E, T, cursor, nb);
    gather_f32    <<<(N + 3) / 4, 256, 0, stream>>>(feat, cnt, offs, nb, agg, N);
    prep_b        <<<512, 256, 0, stream>>>(w_ih, w_hh, Bp);
    gru_gemm      <<<N / BM, 512, 0, stream>>>(agg, mem, Bp, b_ih, b_hh, cnt, out, N);
}